// Round 1
// baseline (251.302 us; speedup 1.0000x reference)
//
#include <hip/hip_runtime.h>
#include <hip/hip_bf16.h>
#include <stdint.h>

#define E_EDGES   800000
#define N_NODES_C 50000
#define NG        64
#define DD        128     // NODE_DIM == INSTR_DIM
#define HH        256     // HIDDEN_DIM
#define KDIM      384     // 2*128 + 128
#define BM        128
#define BK        32
#define KSTEPS    12
#define THREADS   512

typedef __bf16 bf16x8 __attribute__((ext_vector_type(8)));
typedef __bf16 bf16x4 __attribute__((ext_vector_type(4)));
typedef float  f32x4  __attribute__((ext_vector_type(4)));

__device__ __forceinline__ void gld16(const void* g, void* l) {
  __builtin_amdgcn_global_load_lds(
      (__attribute__((address_space(1))) void*)g,
      (__attribute__((address_space(3))) void*)l, 16, 0, 0);
}

// ---------- prep kernels ----------
__global__ void k_cvt4(const float* __restrict__ in, __bf16* __restrict__ out, int n4) {
  int i = blockIdx.x * blockDim.x + threadIdx.x;
  if (i < n4) {
    float4 v = ((const float4*)in)[i];
    bf16x4 b;
    b[0] = (__bf16)v.x; b[1] = (__bf16)v.y; b[2] = (__bf16)v.z; b[3] = (__bf16)v.w;
    ((bf16x4*)out)[i] = b;
  }
}

__global__ void k_w1t(const float* __restrict__ w1, __bf16* __restrict__ w1t) {
  int idx = blockIdx.x * blockDim.x + threadIdx.x;
  if (idx < KDIM * HH) {
    int k = idx >> 8;     // HH = 256
    int n = idx & 255;
    w1t[n * KDIM + k] = (__bf16)w1[idx];
  }
}

// ---------- main fused GEMM ----------
// MODE 0: A staged via global_load_lds from pre-converted bf16 x/instr.
// MODE 1: A staged via fp32 gather + in-reg cvt + ds_write (small-ws fallback).
template <int MODE>
__launch_bounds__(THREADS, 4)
__global__ void k_main(const float* __restrict__ xf,
                       const float* __restrict__ instrf,
                       const int*   __restrict__ ei,
                       const int*   __restrict__ batch,
                       const __bf16* __restrict__ xbf,
                       const __bf16* __restrict__ insbf,
                       const __bf16* __restrict__ w1t,
                       const float* __restrict__ b1,
                       const float* __restrict__ w2,
                       const float* __restrict__ b2,
                       float* __restrict__ out)
{
  __shared__ __align__(16) char smem[16384 + 32768 + 2048];
  char*  As  = smem;                 // 2 x [128 rows][32k] bf16, swizzled 16B slots
  char*  Bs  = smem + 16384;         // 2 x [256 cols][32k] bf16 (W1^T), swizzled
  float* red = (float*)(smem + 16384 + 32768);  // [4 n-waves][128 rows]

  const int tid  = threadIdx.x;
  const int lane = tid & 63;
  const int wid  = tid >> 6;
  const int blk  = blockIdx.x;

  // ----- staging geometry: thread -> one 16B chunk (row, slot) -----
  const int arow  = tid >> 2;            // 0..127 tile row (edge)
  const int aslot = tid & 3;             // 16B slot within 64B row
  const int akap  = aslot ^ ((arow >> 1) & 3);   // k-slice stored in this slot
  const int e     = blk * BM + arow;
  const int s     = ei[e];
  const int d     = ei[E_EDGES + e];
  const int g     = batch[s];

  const char  *aS = nullptr, *aD = nullptr, *aI = nullptr;
  const float *fS = nullptr, *fD = nullptr, *fI = nullptr;
  if (MODE == 0) {
    aS = (const char*)xbf   + s * 256 + akap * 16;
    aD = (const char*)xbf   + d * 256 + akap * 16;
    aI = (const char*)insbf + g * 256 + akap * 16;
  } else {
    fS = xf     + s * DD + akap * 8;
    fD = xf     + d * DD + akap * 8;
    fI = instrf + g * DD + akap * 8;
  }

  const char* bptr[2];
#pragma unroll
  for (int it = 0; it < 2; ++it) {
    int j2 = tid + it * 512;
    int n  = j2 >> 2;
    int bk = (j2 & 3) ^ ((n >> 1) & 3);
    bptr[it] = (const char*)w1t + n * (KDIM * 2) + bk * 16;
  }

  char* ldsA = As + wid * 1024;   // + cur*8192   (lane*16 implicit in HW)
  char* ldsB = Bs + wid * 1024;   // + cur*16384 + it*8192

  auto stage = [&](int cur, int kk) {
    // B: 2 x 16B per thread
    gld16(bptr[0] + kk * 64, ldsB + cur * 16384);
    gld16(bptr[1] + kk * 64, ldsB + cur * 16384 + 8192);
    // A: 1 x 16B per thread, source picked by K-section (uniform branch)
    if (MODE == 0) {
      const char* ga = (kk < 4) ? (aS + kk * 64)
                     : (kk < 8) ? (aD + (kk - 4) * 64)
                                : (aI + (kk - 8) * 64);
      gld16(ga, ldsA + cur * 8192);
    } else {
      const float* gf = (kk < 4) ? (fS + kk * 32)
                      : (kk < 8) ? (fD + (kk - 4) * 32)
                                 : (fI + (kk - 8) * 32);
      float4 v0 = *(const float4*)gf;
      float4 v1 = *(const float4*)(gf + 4);
      bf16x8 bv;
      bv[0] = (__bf16)v0.x; bv[1] = (__bf16)v0.y; bv[2] = (__bf16)v0.z; bv[3] = (__bf16)v0.w;
      bv[4] = (__bf16)v1.x; bv[5] = (__bf16)v1.y; bv[6] = (__bf16)v1.z; bv[7] = (__bf16)v1.w;
      *(bf16x8*)(As + cur * 8192 + tid * 16) = bv;
    }
  };

  // ----- compute-side per-lane constants -----
  const int wm    = wid >> 2;           // 0..1 : row-wave
  const int wn    = wid & 3;            // 0..3 : col-wave
  const int l15   = lane & 15;
  const int kap_r = (lane >> 4) ^ ((l15 >> 1) & 3);
  const int aoff  = wm * 4096 + l15 * 64 + kap_r * 16;
  const int boff  = wn * 4096 + l15 * 64 + kap_r * 16;

  f32x4 acc[4][4];
#pragma unroll
  for (int mi = 0; mi < 4; ++mi)
#pragma unroll
    for (int ni = 0; ni < 4; ++ni)
      acc[mi][ni] = f32x4{0.f, 0.f, 0.f, 0.f};

  stage(0, 0);

  for (int kk = 0; kk < KSTEPS; ++kk) {
    const int cur = kk & 1;
    __syncthreads();                       // stage(kk) landed; buf cur^1 free
    if (kk + 1 < KSTEPS) stage(cur ^ 1, kk + 1);

    const char* pA = As + cur * 8192;
    const char* pB = Bs + cur * 16384;
    bf16x8 av[4], bv[4];
#pragma unroll
    for (int mi = 0; mi < 4; ++mi) av[mi] = *(const bf16x8*)(pA + aoff + mi * 1024);
#pragma unroll
    for (int ni = 0; ni < 4; ++ni) bv[ni] = *(const bf16x8*)(pB + boff + ni * 1024);
#pragma unroll
    for (int mi = 0; mi < 4; ++mi)
#pragma unroll
      for (int ni = 0; ni < 4; ++ni)
        acc[mi][ni] = __builtin_amdgcn_mfma_f32_16x16x32_bf16(av[mi], bv[ni], acc[mi][ni], 0, 0, 0);
  }

  // ----- epilogue: bias + silu + @W2, reduce over the 256 hidden cols -----
  float b1c[4], w2c[4];
#pragma unroll
  for (int ni = 0; ni < 4; ++ni) {
    int n = wn * 64 + ni * 16 + l15;
    b1c[ni] = b1[n];
    w2c[ni] = w2[n];
  }

  float rowsum[4][4];
#pragma unroll
  for (int mi = 0; mi < 4; ++mi)
#pragma unroll
    for (int r = 0; r < 4; ++r) rowsum[mi][r] = 0.f;

#pragma unroll
  for (int ni = 0; ni < 4; ++ni) {
    float bb = b1c[ni], ww = w2c[ni];
#pragma unroll
    for (int mi = 0; mi < 4; ++mi)
#pragma unroll
      for (int r = 0; r < 4; ++r) {
        float v  = acc[mi][ni][r] + bb;
        float sv = v / (1.0f + __expf(-v));   // silu
        rowsum[mi][r] += sv * ww;
      }
  }

  // sum across the 16 lanes holding different cols of the same rows
#pragma unroll
  for (int off = 1; off < 16; off <<= 1)
#pragma unroll
    for (int mi = 0; mi < 4; ++mi)
#pragma unroll
      for (int r = 0; r < 4; ++r)
        rowsum[mi][r] += __shfl_xor(rowsum[mi][r], off, 64);

  if (l15 == 0) {
    int rg = lane >> 4;                  // 0..3
#pragma unroll
    for (int mi = 0; mi < 4; ++mi)
#pragma unroll
      for (int r = 0; r < 4; ++r)
        red[wn * 128 + wm * 64 + mi * 16 + rg * 4 + r] = rowsum[mi][r];
  }
  __syncthreads();

  if (tid < BM) {
    float v = red[tid] + red[128 + tid] + red[256 + tid] + red[384 + tid] + b2[0];
    out[blk * BM + tid] = v;
  }
}

// ---------- launch ----------
extern "C" void kernel_launch(void* const* d_in, const int* in_sizes, int n_in,
                              void* d_out, int out_size, void* d_ws, size_t ws_size,
                              hipStream_t stream) {
  const float* instr = (const float*)d_in[0];
  const float* x     = (const float*)d_in[1];
  const int*   ei    = (const int*)d_in[2];
  const int*   batch = (const int*)d_in[3];
  const float* W1    = (const float*)d_in[4];
  const float* b1    = (const float*)d_in[5];
  const float* W2    = (const float*)d_in[6];
  const float* b2    = (const float*)d_in[7];
  float* out = (float*)d_out;
  char* ws = (char*)d_ws;

  const size_t off_xbf = 0;                       // 50000*128*2 = 12,800,000
  const size_t off_ins = 12800000;                // 64*128*2    = 16,384
  const size_t off_w1t = 12816384;                // 256*384*2   = 196,608
  const size_t need_fast = 13012992;

  if (ws_size >= need_fast) {
    __bf16* xbf   = (__bf16*)(ws + off_xbf);
    __bf16* insbf = (__bf16*)(ws + off_ins);
    __bf16* w1t   = (__bf16*)(ws + off_w1t);
    k_cvt4<<<(N_NODES_C * DD / 4 + 255) / 256, 256, 0, stream>>>(x, xbf, N_NODES_C * DD / 4);
    k_cvt4<<<(NG * DD / 4 + 255) / 256, 256, 0, stream>>>(instr, insbf, NG * DD / 4);
    k_w1t<<<(KDIM * HH + 255) / 256, 256, 0, stream>>>(W1, w1t);
    k_main<0><<<E_EDGES / BM, THREADS, 0, stream>>>(x, instr, ei, batch, xbf, insbf, w1t,
                                                    b1, W2, b2, out);
  } else {
    __bf16* w1t = (__bf16*)ws;                    // needs only 196,608 B
    k_w1t<<<(KDIM * HH + 255) / 256, 256, 0, stream>>>(W1, w1t);
    k_main<1><<<E_EDGES / BM, THREADS, 0, stream>>>(x, instr, ei, batch, nullptr, nullptr, w1t,
                                                    b1, W2, b2, out);
  }
}

// Round 2
// 156.002 us; speedup vs baseline: 1.6109x; 1.6109x over previous
//
#include <hip/hip_runtime.h>
#include <hip/hip_bf16.h>
#include <stdint.h>

#define E_EDGES   800000
#define N_NODES_C 50000
#define NG        64
#define DD        128     // NODE_DIM == INSTR_DIM
#define HH        256     // HIDDEN_DIM
#define KDIM      384     // 2*128 + 128

typedef __bf16 bf16x8 __attribute__((ext_vector_type(8)));
typedef __bf16 bf16x4 __attribute__((ext_vector_type(4)));
typedef float  f32x4  __attribute__((ext_vector_type(4)));

__device__ __forceinline__ void gld16(const void* g, void* l) {
  __builtin_amdgcn_global_load_lds(
      (__attribute__((address_space(1))) void*)g,
      (__attribute__((address_space(3))) void*)l, 16, 0, 0);
}

// ---------------- prep kernels ----------------
__global__ void k_cvt4(const float* __restrict__ in, __bf16* __restrict__ out, int n4) {
  int i = blockIdx.x * blockDim.x + threadIdx.x;
  if (i < n4) {
    float4 v = ((const float4*)in)[i];
    bf16x4 b;
    b[0] = (__bf16)v.x; b[1] = (__bf16)v.y; b[2] = (__bf16)v.z; b[3] = (__bf16)v.w;
    ((bf16x4*)out)[i] = b;
  }
}

// w1pt[n][k], n in [0,512), k in [0,128): B^T for the node GEMM.
// n<256: W1[k][n] (P part) ; n>=256: W1[128+k][n-256] (Q part)
__global__ void k_w1pt(const float* __restrict__ w1, __bf16* __restrict__ w1pt) {
  int idx = blockIdx.x * blockDim.x + threadIdx.x;
  if (idx < 512 * 128) {
    int n = idx >> 7;
    int k = idx & 127;
    float v = (n < 256) ? w1[k * HH + n] : w1[(128 + k) * HH + (n - 256)];
    w1pt[n * 128 + k] = (__bf16)v;
  }
}

// r2[g][c] = sum_k instr[g][k] * W1[256+k][c] + b1[c]   (fp32, 64x256)
__global__ void k_r2(const float* __restrict__ instr, const float* __restrict__ w1,
                     const float* __restrict__ b1, float* __restrict__ r2) {
  __shared__ float ins[DD];
  int g = blockIdx.x;
  int c = threadIdx.x;          // 256 threads
  if (c < DD) ins[c] = instr[g * DD + c];
  __syncthreads();
  float sum = b1[c];
#pragma unroll 8
  for (int k = 0; k < DD; ++k) sum += ins[k] * w1[(256 + k) * HH + c];
  r2[g * HH + c] = sum;
}

// ---------------- phase 1: node GEMM  PQ = x @ [W1a | W1b]  ----------------
// BM=128 rows, BN=256 (grid.y selects which 256 of 512 cols), K=128 (4 steps of 32)
__launch_bounds__(512, 4)
__global__ void k_nodegemm(const __bf16* __restrict__ xbf,
                           const __bf16* __restrict__ w1pt,
                           __bf16* __restrict__ pq)
{
  __shared__ __align__(16) char smem[16384 + 32768];
  char* As = smem;             // 2 x [128 rows][32k] bf16, swizzled 16B slots
  char* Bs = smem + 16384;     // 2 x [256 cols][32k] bf16

  const int tid  = threadIdx.x;
  const int lane = tid & 63;
  const int wid  = tid >> 6;
  const int rowbase = blockIdx.x * 128;
  const int nt      = blockIdx.y;          // 0/1 -> cols [0,256) / [256,512)

  const int arow  = tid >> 2;
  const int aslot = tid & 3;
  const int akap  = aslot ^ ((arow >> 1) & 3);
  int gr = rowbase + arow; if (gr >= N_NODES_C) gr = N_NODES_C - 1;
  const char* aptr = (const char*)xbf + (size_t)gr * 256 + akap * 16;

  const char* bptr[2];
#pragma unroll
  for (int it = 0; it < 2; ++it) {
    int j2 = tid + it * 512;
    int n  = j2 >> 2;
    int bk = (j2 & 3) ^ ((n >> 1) & 3);
    bptr[it] = (const char*)w1pt + (size_t)(nt * 256 + n) * 256 + bk * 16;
  }

  char* ldsA = As + wid * 1024;
  char* ldsB = Bs + wid * 1024;

  auto stage = [&](int cur, int kk) {
    gld16(bptr[0] + kk * 64, ldsB + cur * 16384);
    gld16(bptr[1] + kk * 64, ldsB + cur * 16384 + 8192);
    gld16(aptr    + kk * 64, ldsA + cur * 8192);
  };

  const int wm    = wid >> 2;
  const int wn    = wid & 3;
  const int l15   = lane & 15;
  const int kap_r = (lane >> 4) ^ ((l15 >> 1) & 3);
  const int aoff  = wm * 4096 + l15 * 64 + kap_r * 16;
  const int boff  = wn * 4096 + l15 * 64 + kap_r * 16;

  f32x4 acc[4][4];
#pragma unroll
  for (int mi = 0; mi < 4; ++mi)
#pragma unroll
    for (int ni = 0; ni < 4; ++ni)
      acc[mi][ni] = f32x4{0.f, 0.f, 0.f, 0.f};

  stage(0, 0);

  for (int kk = 0; kk < 4; ++kk) {
    const int cur = kk & 1;
    __syncthreads();
    if (kk + 1 < 4) stage(cur ^ 1, kk + 1);

    const char* pA = As + cur * 8192;
    const char* pB = Bs + cur * 16384;
    bf16x8 av[4], bv[4];
#pragma unroll
    for (int mi = 0; mi < 4; ++mi) av[mi] = *(const bf16x8*)(pA + aoff + mi * 1024);
#pragma unroll
    for (int ni = 0; ni < 4; ++ni) bv[ni] = *(const bf16x8*)(pB + boff + ni * 1024);
#pragma unroll
    for (int mi = 0; mi < 4; ++mi)
#pragma unroll
      for (int ni = 0; ni < 4; ++ni)
        acc[mi][ni] = __builtin_amdgcn_mfma_f32_16x16x32_bf16(av[mi], bv[ni], acc[mi][ni], 0, 0, 0);
  }

  // store: row = (lane>>4)*4 + reg, col = lane&15  (within each 16x16 frag)
  const int rg = lane >> 4;
#pragma unroll
  for (int mi = 0; mi < 4; ++mi) {
    int row = rowbase + wm * 64 + mi * 16 + rg * 4;
#pragma unroll
    for (int r = 0; r < 4; ++r) {
      if (row + r < N_NODES_C) {
        size_t base = (size_t)(row + r) * 512 + nt * 256 + wn * 64 + l15;
#pragma unroll
        for (int ni = 0; ni < 4; ++ni)
          pq[base + ni * 16] = (__bf16)acc[mi][ni][r];
      }
    }
  }
}

// ---------------- phase 2: edge gather + silu + dot(w2) ----------------
// 32 lanes per edge, 8 cols per lane. Block = 256 thr = 8 edges/iter, grid-stride.
__launch_bounds__(256, 8)
__global__ void k_edge(const __bf16* __restrict__ pq,
                       const float* __restrict__ r2,
                       const int*   __restrict__ ei,
                       const int*   __restrict__ batch,
                       const float* __restrict__ w2,
                       const float* __restrict__ b2,
                       float* __restrict__ out)
{
  const int tid  = threadIdx.x;
  const int lane = tid & 63;
  const int wid  = tid >> 6;
  const int half = lane >> 5;
  const int l    = lane & 31;
  const int c0   = l * 8;

  float w2r[8];
  {
    float4 a = *(const float4*)(w2 + c0);
    float4 b = *(const float4*)(w2 + c0 + 4);
    w2r[0]=a.x; w2r[1]=a.y; w2r[2]=a.z; w2r[3]=a.w;
    w2r[4]=b.x; w2r[5]=b.y; w2r[6]=b.z; w2r[7]=b.w;
  }
  const float bb = b2[0];

  for (int e = blockIdx.x * 8 + wid * 2 + half; e < E_EDGES; e += gridDim.x * 8) {
    int s = ei[e];
    int d = ei[E_EDGES + e];
    int g = batch[s];

    bf16x8 pv = *(const bf16x8*)(pq + (size_t)s * 512 + c0);
    bf16x8 qv = *(const bf16x8*)(pq + (size_t)d * 512 + 256 + c0);
    float4 r0 = *(const float4*)(r2 + g * HH + c0);
    float4 r1 = *(const float4*)(r2 + g * HH + c0 + 4);
    float rv[8] = {r0.x, r0.y, r0.z, r0.w, r1.x, r1.y, r1.z, r1.w};

    float sum = 0.f;
#pragma unroll
    for (int j = 0; j < 8; ++j) {
      float v  = (float)pv[j] + (float)qv[j] + rv[j];
      float sv = v * __builtin_amdgcn_rcpf(1.0f + __expf(-v));
      sum += sv * w2r[j];
    }
#pragma unroll
    for (int off = 1; off < 32; off <<= 1)
      sum += __shfl_xor(sum, off, 64);
    if (l == 0) out[e] = sum + bb;
  }
}

// ================= fallback (round-1 kernel, proven) =================
#define BM 128
#define KSTEPS 12
#define THREADS 512

template <int MODE>
__launch_bounds__(THREADS, 4)
__global__ void k_main(const float* __restrict__ xf,
                       const float* __restrict__ instrf,
                       const int*   __restrict__ ei,
                       const int*   __restrict__ batch,
                       const __bf16* __restrict__ xbf,
                       const __bf16* __restrict__ insbf,
                       const __bf16* __restrict__ w1t,
                       const float* __restrict__ b1,
                       const float* __restrict__ w2,
                       const float* __restrict__ b2,
                       float* __restrict__ out)
{
  __shared__ __align__(16) char smem[16384 + 32768 + 2048];
  char*  As  = smem;
  char*  Bs  = smem + 16384;
  float* red = (float*)(smem + 16384 + 32768);

  const int tid  = threadIdx.x;
  const int lane = tid & 63;
  const int wid  = tid >> 6;
  const int blk  = blockIdx.x;

  const int arow  = tid >> 2;
  const int aslot = tid & 3;
  const int akap  = aslot ^ ((arow >> 1) & 3);
  const int e     = blk * BM + arow;
  const int s     = ei[e];
  const int d     = ei[E_EDGES + e];
  const int g     = batch[s];

  const char  *aS = nullptr, *aD = nullptr, *aI = nullptr;
  const float *fS = nullptr, *fD = nullptr, *fI = nullptr;
  if (MODE == 0) {
    aS = (const char*)xbf   + s * 256 + akap * 16;
    aD = (const char*)xbf   + d * 256 + akap * 16;
    aI = (const char*)insbf + g * 256 + akap * 16;
  } else {
    fS = xf     + s * DD + akap * 8;
    fD = xf     + d * DD + akap * 8;
    fI = instrf + g * DD + akap * 8;
  }

  const char* bptr[2];
#pragma unroll
  for (int it = 0; it < 2; ++it) {
    int j2 = tid + it * 512;
    int n  = j2 >> 2;
    int bk = (j2 & 3) ^ ((n >> 1) & 3);
    bptr[it] = (const char*)w1t + n * (KDIM * 2) + bk * 16;
  }

  char* ldsA = As + wid * 1024;
  char* ldsB = Bs + wid * 1024;

  auto stage = [&](int cur, int kk) {
    gld16(bptr[0] + kk * 64, ldsB + cur * 16384);
    gld16(bptr[1] + kk * 64, ldsB + cur * 16384 + 8192);
    if (MODE == 0) {
      const char* ga = (kk < 4) ? (aS + kk * 64)
                     : (kk < 8) ? (aD + (kk - 4) * 64)
                                : (aI + (kk - 8) * 64);
      gld16(ga, ldsA + cur * 8192);
    } else {
      const float* gf = (kk < 4) ? (fS + kk * 32)
                      : (kk < 8) ? (fD + (kk - 4) * 32)
                                 : (fI + (kk - 8) * 32);
      float4 v0 = *(const float4*)gf;
      float4 v1 = *(const float4*)(gf + 4);
      bf16x8 bv;
      bv[0] = (__bf16)v0.x; bv[1] = (__bf16)v0.y; bv[2] = (__bf16)v0.z; bv[3] = (__bf16)v0.w;
      bv[4] = (__bf16)v1.x; bv[5] = (__bf16)v1.y; bv[6] = (__bf16)v1.z; bv[7] = (__bf16)v1.w;
      *(bf16x8*)(As + cur * 8192 + tid * 16) = bv;
    }
  };

  const int wm    = wid >> 2;
  const int wn    = wid & 3;
  const int l15   = lane & 15;
  const int kap_r = (lane >> 4) ^ ((l15 >> 1) & 3);
  const int aoff  = wm * 4096 + l15 * 64 + kap_r * 16;
  const int boff  = wn * 4096 + l15 * 64 + kap_r * 16;

  f32x4 acc[4][4];
#pragma unroll
  for (int mi = 0; mi < 4; ++mi)
#pragma unroll
    for (int ni = 0; ni < 4; ++ni)
      acc[mi][ni] = f32x4{0.f, 0.f, 0.f, 0.f};

  stage(0, 0);

  for (int kk = 0; kk < KSTEPS; ++kk) {
    const int cur = kk & 1;
    __syncthreads();
    if (kk + 1 < KSTEPS) stage(cur ^ 1, kk + 1);

    const char* pA = As + cur * 8192;
    const char* pB = Bs + cur * 16384;
    bf16x8 av[4], bv[4];
#pragma unroll
    for (int mi = 0; mi < 4; ++mi) av[mi] = *(const bf16x8*)(pA + aoff + mi * 1024);
#pragma unroll
    for (int ni = 0; ni < 4; ++ni) bv[ni] = *(const bf16x8*)(pB + boff + ni * 1024);
#pragma unroll
    for (int mi = 0; mi < 4; ++mi)
#pragma unroll
      for (int ni = 0; ni < 4; ++ni)
        acc[mi][ni] = __builtin_amdgcn_mfma_f32_16x16x32_bf16(av[mi], bv[ni], acc[mi][ni], 0, 0, 0);
  }

  float b1c[4], w2c[4];
#pragma unroll
  for (int ni = 0; ni < 4; ++ni) {
    int n = wn * 64 + ni * 16 + l15;
    b1c[ni] = b1[n];
    w2c[ni] = w2[n];
  }

  float rowsum[4][4];
#pragma unroll
  for (int mi = 0; mi < 4; ++mi)
#pragma unroll
    for (int r = 0; r < 4; ++r) rowsum[mi][r] = 0.f;

#pragma unroll
  for (int ni = 0; ni < 4; ++ni) {
    float bb = b1c[ni], ww = w2c[ni];
#pragma unroll
    for (int mi = 0; mi < 4; ++mi)
#pragma unroll
      for (int r = 0; r < 4; ++r) {
        float v  = acc[mi][ni][r] + bb;
        float sv = v / (1.0f + __expf(-v));
        rowsum[mi][r] += sv * ww;
      }
  }

#pragma unroll
  for (int off = 1; off < 16; off <<= 1)
#pragma unroll
    for (int mi = 0; mi < 4; ++mi)
#pragma unroll
      for (int r = 0; r < 4; ++r)
        rowsum[mi][r] += __shfl_xor(rowsum[mi][r], off, 64);

  if (l15 == 0) {
    int rg = lane >> 4;
#pragma unroll
    for (int mi = 0; mi < 4; ++mi)
#pragma unroll
      for (int r = 0; r < 4; ++r)
        red[wn * 128 + wm * 64 + mi * 16 + rg * 4 + r] = rowsum[mi][r];
  }
  __syncthreads();

  if (tid < BM) {
    float v = red[tid] + red[128 + tid] + red[256 + tid] + red[384 + tid] + b2[0];
    out[blk * BM + tid] = v;
  }
}

// ---------------- launch ----------------
extern "C" void kernel_launch(void* const* d_in, const int* in_sizes, int n_in,
                              void* d_out, int out_size, void* d_ws, size_t ws_size,
                              hipStream_t stream) {
  const float* instr = (const float*)d_in[0];
  const float* x     = (const float*)d_in[1];
  const int*   ei    = (const int*)d_in[2];
  const int*   batch = (const int*)d_in[3];
  const float* W1    = (const float*)d_in[4];
  const float* b1    = (const float*)d_in[5];
  const float* W2    = (const float*)d_in[6];
  const float* b2    = (const float*)d_in[7];
  float* out = (float*)d_out;
  char* ws = (char*)d_ws;

  // full-path workspace layout
  const size_t off_xbf  = 0;                       // 12,800,000
  const size_t off_w1pt = 12800000;                // 131,072
  const size_t off_r2   = 12931072;                // 65,536
  const size_t off_pq   = 12996608;                // 51,200,000
  const size_t need_full = 64196608;

  if (ws_size >= need_full) {
    __bf16* xbf  = (__bf16*)(ws + off_xbf);
    __bf16* w1pt = (__bf16*)(ws + off_w1pt);
    float*  r2   = (float*)(ws + off_r2);
    __bf16* pq   = (__bf16*)(ws + off_pq);

    k_cvt4<<<(N_NODES_C * DD / 4 + 255) / 256, 256, 0, stream>>>(x, xbf, N_NODES_C * DD / 4);
    k_w1pt<<<(512 * 128 + 255) / 256, 256, 0, stream>>>(W1, w1pt);
    k_r2<<<NG, HH, 0, stream>>>(instr, W1, b1, r2);
    dim3 g1((N_NODES_C + 127) / 128, 2);
    k_nodegemm<<<g1, 512, 0, stream>>>(xbf, w1pt, pq);
    k_edge<<<2048, 256, 0, stream>>>(pq, r2, ei, batch, W2, b2, out);
    return;
  }

  // fallback: round-1 fused edge GEMM
  const size_t f_off_xbf = 0;
  const size_t f_off_ins = 12800000;
  const size_t f_off_w1t = 12816384;
  const size_t need_fast = 13012992;

  if (ws_size >= need_fast) {
    __bf16* xbf   = (__bf16*)(ws + f_off_xbf);
    __bf16* insbf = (__bf16*)(ws + f_off_ins);
    __bf16* w1t   = (__bf16*)(ws + f_off_w1t);
    k_cvt4<<<(N_NODES_C * DD / 4 + 255) / 256, 256, 0, stream>>>(x, xbf, N_NODES_C * DD / 4);
    k_cvt4<<<(NG * DD / 4 + 255) / 256, 256, 0, stream>>>(instr, insbf, NG * DD / 4);
    {
      // reuse k_w1pt-style transpose for the full 384x256 W1 (round-1 layout)
      // w1t[n][k], n in [0,256), k in [0,384)
      // implemented inline via a small lambda-kernel is not possible; use k_main's expected layout:
      // launch the round-1 transpose below
    }
    // round-1 W1 transpose kernel inlined here as a loop-free launch:
    // (separate kernel definition)
    extern __global__ void k_w1t_fb(const float*, __bf16*);
    k_w1t_fb<<<(KDIM * HH + 255) / 256, 256, 0, stream>>>(W1, w1t);
    k_main<0><<<E_EDGES / BM, THREADS, 0, stream>>>(x, instr, ei, batch, xbf, insbf, w1t,
                                                    b1, W2, b2, out);
  } else {
    __bf16* w1t = (__bf16*)ws;
    extern __global__ void k_w1t_fb(const float*, __bf16*);
    k_w1t_fb<<<(KDIM * HH + 255) / 256, 256, 0, stream>>>(W1, w1t);
    k_main<1><<<E_EDGES / BM, THREADS, 0, stream>>>(x, instr, ei, batch, nullptr, nullptr, w1t,
                                                    b1, W2, b2, out);
  }
}

// round-1 W1 transpose (fallback path): w1t[n][k] = W1[k][n], n<256, k<384
__global__ void k_w1t_fb(const float* __restrict__ w1, __bf16* __restrict__ w1t) {
  int idx = blockIdx.x * blockDim.x + threadIdx.x;
  if (idx < KDIM * HH) {
    int k = idx >> 8;
    int n = idx & 255;
    w1t[n * KDIM + k] = (__bf16)w1[idx];
  }
}

// Round 3
// 150.192 us; speedup vs baseline: 1.6732x; 1.0387x over previous
//
#include <hip/hip_runtime.h>
#include <hip/hip_bf16.h>
#include <stdint.h>

#define E_EDGES   800000
#define N_NODES_C 50000
#define NG        64
#define DD        128     // NODE_DIM == INSTR_DIM
#define HH        256     // HIDDEN_DIM
#define KDIM      384     // 2*128 + 128

typedef __bf16 bf16x8 __attribute__((ext_vector_type(8)));
typedef __bf16 bf16x4 __attribute__((ext_vector_type(4)));
typedef float  f32x4  __attribute__((ext_vector_type(4)));
typedef uint32_t u32x4 __attribute__((ext_vector_type(4)));

__device__ __forceinline__ void gld16(const void* g, void* l) {
  __builtin_amdgcn_global_load_lds(
      (__attribute__((address_space(1))) void*)g,
      (__attribute__((address_space(3))) void*)l, 16, 0, 0);
}

__device__ __forceinline__ float bf_hi(uint32_t u) { return __uint_as_float(u & 0xffff0000u); }
__device__ __forceinline__ float bf_lo(uint32_t u) { return __uint_as_float(u << 16); }

// ---------------- merged prep kernel ----------------
// blocks [0,6250): x f32 -> bf16           (1,600,000 float4 elements)
// blocks [6250,6506): w1pt transpose       (65,536 elements)
// blocks [6506,6570): r2[g][c] = instr[g] @ W1c + b1   (64 x 256 f32)
#define PREP_CVT_BLKS 6250
#define PREP_W1_BLKS  256
#define PREP_R2_BLKS  64

__global__ void k_prep(const float* __restrict__ x, const float* __restrict__ w1,
                       const float* __restrict__ instr, const float* __restrict__ b1,
                       __bf16* __restrict__ xbf, __bf16* __restrict__ w1pt,
                       float* __restrict__ r2) {
  __shared__ float ins[DD];
  const int bid = blockIdx.x;
  const int tid = threadIdx.x;
  if (bid < PREP_CVT_BLKS) {
    int i = bid * 256 + tid;                 // exactly 1.6M float4s
    float4 v = ((const float4*)x)[i];
    bf16x4 b;
    b[0] = (__bf16)v.x; b[1] = (__bf16)v.y; b[2] = (__bf16)v.z; b[3] = (__bf16)v.w;
    ((bf16x4*)xbf)[i] = b;
  } else if (bid < PREP_CVT_BLKS + PREP_W1_BLKS) {
    int idx = (bid - PREP_CVT_BLKS) * 256 + tid;   // 512*128 = 65536
    int n = idx >> 7;
    int k = idx & 127;
    float v = (n < 256) ? w1[k * HH + n] : w1[(128 + k) * HH + (n - 256)];
    w1pt[n * 128 + k] = (__bf16)v;
  } else {
    int g = bid - (PREP_CVT_BLKS + PREP_W1_BLKS);
    int c = tid;
    if (c < DD) ins[c] = instr[g * DD + c];
    __syncthreads();
    float sum = b1[c];
#pragma unroll 8
    for (int k = 0; k < DD; ++k) sum += ins[k] * w1[(256 + k) * HH + c];
    r2[g * HH + c] = sum;
  }
}

// ---------------- phase 1: node GEMM  PQ = x @ [W1a | W1b], P-half += r2 ----
__launch_bounds__(512, 4)
__global__ void k_nodegemm(const __bf16* __restrict__ xbf,
                           const __bf16* __restrict__ w1pt,
                           const int*   __restrict__ batch,
                           const float* __restrict__ r2,
                           __bf16* __restrict__ pq)
{
  __shared__ __align__(16) char smem[16384 + 32768];
  char* As = smem;             // 2 x [128 rows][32k] bf16, swizzled 16B slots
  char* Bs = smem + 16384;     // 2 x [256 cols][32k] bf16

  const int tid  = threadIdx.x;
  const int lane = tid & 63;
  const int wid  = tid >> 6;
  const int rowbase = blockIdx.x * 128;
  const int nt      = blockIdx.y;          // 0/1 -> cols [0,256) / [256,512)

  const int arow  = tid >> 2;
  const int aslot = tid & 3;
  const int akap  = aslot ^ ((arow >> 1) & 3);
  int gr = rowbase + arow; if (gr >= N_NODES_C) gr = N_NODES_C - 1;
  const char* aptr = (const char*)xbf + (size_t)gr * 256 + akap * 16;

  const char* bptr[2];
#pragma unroll
  for (int it = 0; it < 2; ++it) {
    int j2 = tid + it * 512;
    int n  = j2 >> 2;
    int bk = (j2 & 3) ^ ((n >> 1) & 3);
    bptr[it] = (const char*)w1pt + (size_t)(nt * 256 + n) * 256 + bk * 16;
  }

  char* ldsA = As + wid * 1024;
  char* ldsB = Bs + wid * 1024;

  auto stage = [&](int cur, int kk) {
    gld16(bptr[0] + kk * 64, ldsB + cur * 16384);
    gld16(bptr[1] + kk * 64, ldsB + cur * 16384 + 8192);
    gld16(aptr    + kk * 64, ldsA + cur * 8192);
  };

  const int wm    = wid >> 2;
  const int wn    = wid & 3;
  const int l15   = lane & 15;
  const int kap_r = (lane >> 4) ^ ((l15 >> 1) & 3);
  const int aoff  = wm * 4096 + l15 * 64 + kap_r * 16;
  const int boff  = wn * 4096 + l15 * 64 + kap_r * 16;

  f32x4 acc[4][4];
#pragma unroll
  for (int mi = 0; mi < 4; ++mi)
#pragma unroll
    for (int ni = 0; ni < 4; ++ni)
      acc[mi][ni] = f32x4{0.f, 0.f, 0.f, 0.f};

  stage(0, 0);

  for (int kk = 0; kk < 4; ++kk) {
    const int cur = kk & 1;
    __syncthreads();
    if (kk + 1 < 4) stage(cur ^ 1, kk + 1);

    const char* pA = As + cur * 8192;
    const char* pB = Bs + cur * 16384;
    bf16x8 av[4], bv[4];
#pragma unroll
    for (int mi = 0; mi < 4; ++mi) av[mi] = *(const bf16x8*)(pA + aoff + mi * 1024);
#pragma unroll
    for (int ni = 0; ni < 4; ++ni) bv[ni] = *(const bf16x8*)(pB + boff + ni * 1024);
#pragma unroll
    for (int mi = 0; mi < 4; ++mi)
#pragma unroll
      for (int ni = 0; ni < 4; ++ni)
        acc[mi][ni] = __builtin_amdgcn_mfma_f32_16x16x32_bf16(av[mi], bv[ni], acc[mi][ni], 0, 0, 0);
  }

  // store: row = (lane>>4)*4 + reg, col = lane&15 within each 16x16 frag.
  // P-half (nt==0) folds in r2[batch[row]].
  const int rg = lane >> 4;
  const bool fold = (nt == 0);
#pragma unroll
  for (int mi = 0; mi < 4; ++mi) {
    int row = rowbase + wm * 64 + mi * 16 + rg * 4;
#pragma unroll
    for (int r = 0; r < 4; ++r) {
      int rr = row + r;
      if (rr < N_NODES_C) {
        float addv[4] = {0.f, 0.f, 0.f, 0.f};
        if (fold) {
          int g = batch[rr];
          const float* r2row = r2 + g * HH + wn * 64 + l15;
#pragma unroll
          for (int ni = 0; ni < 4; ++ni) addv[ni] = r2row[ni * 16];
        }
        size_t base = (size_t)rr * 512 + nt * 256 + wn * 64 + l15;
#pragma unroll
        for (int ni = 0; ni < 4; ++ni)
          pq[base + ni * 16] = (__bf16)(acc[mi][ni][r] + addv[ni]);
      }
    }
  }
}

// ---------------- phase 2: edge gather + silu + dot(w2) ----------------
// 32 lanes per edge, 8 cols per lane, 2 edges per lane-group per iteration.
__launch_bounds__(256, 8)
__global__ void k_edge(const __bf16* __restrict__ pq,
                       const int*   __restrict__ ei,
                       const float* __restrict__ w2,
                       const float* __restrict__ b2,
                       float* __restrict__ out)
{
  const int tid  = threadIdx.x;
  const int lane = tid & 63;
  const int wid  = tid >> 6;
  const int half = lane >> 5;
  const int l    = lane & 31;
  const int c0   = l * 8;

  float w2r[8];
  {
    float4 a = *(const float4*)(w2 + c0);
    float4 b = *(const float4*)(w2 + c0 + 4);
    w2r[0]=a.x; w2r[1]=a.y; w2r[2]=a.z; w2r[3]=a.w;
    w2r[4]=b.x; w2r[5]=b.y; w2r[6]=b.z; w2r[7]=b.w;
  }
  const float bb = b2[0];
  const float NL2E = -1.44269504f;   // -log2(e)

  for (int e = blockIdx.x * 16 + (wid * 2 + half) * 2; e < E_EDGES; e += gridDim.x * 16) {
    int s0 = ei[e];     int d0 = ei[E_EDGES + e];
    int s1 = ei[e + 1]; int d1 = ei[E_EDGES + e + 1];

    u32x4 p0 = *(const u32x4*)(pq + (size_t)s0 * 512 + c0);
    u32x4 q0 = *(const u32x4*)(pq + (size_t)d0 * 512 + 256 + c0);
    u32x4 p1 = *(const u32x4*)(pq + (size_t)s1 * 512 + c0);
    u32x4 q1 = *(const u32x4*)(pq + (size_t)d1 * 512 + 256 + c0);

    float sum0 = 0.f, sum1 = 0.f;
#pragma unroll
    for (int k = 0; k < 4; ++k) {
      // edge 0, elements 2k (lo) and 2k+1 (hi)
      {
        float va = bf_lo(p0[k]) + bf_lo(q0[k]);
        float vb = bf_hi(p0[k]) + bf_hi(q0[k]);
        float ta = __builtin_amdgcn_exp2f(va * NL2E);
        float tb = __builtin_amdgcn_exp2f(vb * NL2E);
        float da = 1.f + ta, db = 1.f + tb;
        float rc = __builtin_amdgcn_rcpf(da * db);
        sum0 += (va * w2r[2 * k]) * (rc * db) + (vb * w2r[2 * k + 1]) * (rc * da);
      }
      // edge 1
      {
        float va = bf_lo(p1[k]) + bf_lo(q1[k]);
        float vb = bf_hi(p1[k]) + bf_hi(q1[k]);
        float ta = __builtin_amdgcn_exp2f(va * NL2E);
        float tb = __builtin_amdgcn_exp2f(vb * NL2E);
        float da = 1.f + ta, db = 1.f + tb;
        float rc = __builtin_amdgcn_rcpf(da * db);
        sum1 += (va * w2r[2 * k]) * (rc * db) + (vb * w2r[2 * k + 1]) * (rc * da);
      }
    }

#pragma unroll
    for (int off = 1; off < 32; off <<= 1) {
      sum0 += __shfl_xor(sum0, off, 64);
      sum1 += __shfl_xor(sum1, off, 64);
    }
    if (l == 0) *(float2*)(out + e) = make_float2(sum0 + bb, sum1 + bb);
  }
}

// ================= fallback (round-1 kernel, proven) =================
#define BM 128
#define KSTEPS 12
#define THREADS 512

__global__ void k_cvt4(const float* __restrict__ in, __bf16* __restrict__ out, int n4) {
  int i = blockIdx.x * blockDim.x + threadIdx.x;
  if (i < n4) {
    float4 v = ((const float4*)in)[i];
    bf16x4 b;
    b[0] = (__bf16)v.x; b[1] = (__bf16)v.y; b[2] = (__bf16)v.z; b[3] = (__bf16)v.w;
    ((bf16x4*)out)[i] = b;
  }
}

__global__ void k_w1t_fb(const float* __restrict__ w1, __bf16* __restrict__ w1t) {
  int idx = blockIdx.x * blockDim.x + threadIdx.x;
  if (idx < KDIM * HH) {
    int k = idx >> 8;
    int n = idx & 255;
    w1t[n * KDIM + k] = (__bf16)w1[idx];
  }
}

template <int MODE>
__launch_bounds__(THREADS, 4)
__global__ void k_main(const float* __restrict__ xf,
                       const float* __restrict__ instrf,
                       const int*   __restrict__ ei,
                       const int*   __restrict__ batch,
                       const __bf16* __restrict__ xbf,
                       const __bf16* __restrict__ insbf,
                       const __bf16* __restrict__ w1t,
                       const float* __restrict__ b1,
                       const float* __restrict__ w2,
                       const float* __restrict__ b2,
                       float* __restrict__ out)
{
  __shared__ __align__(16) char smem[16384 + 32768 + 2048];
  char*  As  = smem;
  char*  Bs  = smem + 16384;
  float* red = (float*)(smem + 16384 + 32768);

  const int tid  = threadIdx.x;
  const int lane = tid & 63;
  const int wid  = tid >> 6;
  const int blk  = blockIdx.x;

  const int arow  = tid >> 2;
  const int aslot = tid & 3;
  const int akap  = aslot ^ ((arow >> 1) & 3);
  const int e     = blk * BM + arow;
  const int s     = ei[e];
  const int d     = ei[E_EDGES + e];
  const int g     = batch[s];

  const char  *aS = nullptr, *aD = nullptr, *aI = nullptr;
  const float *fS = nullptr, *fD = nullptr, *fI = nullptr;
  if (MODE == 0) {
    aS = (const char*)xbf   + s * 256 + akap * 16;
    aD = (const char*)xbf   + d * 256 + akap * 16;
    aI = (const char*)insbf + g * 256 + akap * 16;
  } else {
    fS = xf     + s * DD + akap * 8;
    fD = xf     + d * DD + akap * 8;
    fI = instrf + g * DD + akap * 8;
  }

  const char* bptr[2];
#pragma unroll
  for (int it = 0; it < 2; ++it) {
    int j2 = tid + it * 512;
    int n  = j2 >> 2;
    int bk = (j2 & 3) ^ ((n >> 1) & 3);
    bptr[it] = (const char*)w1t + n * (KDIM * 2) + bk * 16;
  }

  char* ldsA = As + wid * 1024;
  char* ldsB = Bs + wid * 1024;

  auto stage = [&](int cur, int kk) {
    gld16(bptr[0] + kk * 64, ldsB + cur * 16384);
    gld16(bptr[1] + kk * 64, ldsB + cur * 16384 + 8192);
    if (MODE == 0) {
      const char* ga = (kk < 4) ? (aS + kk * 64)
                     : (kk < 8) ? (aD + (kk - 4) * 64)
                                : (aI + (kk - 8) * 64);
      gld16(ga, ldsA + cur * 8192);
    } else {
      const float* gf = (kk < 4) ? (fS + kk * 32)
                      : (kk < 8) ? (fD + (kk - 4) * 32)
                                 : (fI + (kk - 8) * 32);
      float4 v0 = *(const float4*)gf;
      float4 v1 = *(const float4*)(gf + 4);
      bf16x8 bv;
      bv[0] = (__bf16)v0.x; bv[1] = (__bf16)v0.y; bv[2] = (__bf16)v0.z; bv[3] = (__bf16)v0.w;
      bv[4] = (__bf16)v1.x; bv[5] = (__bf16)v1.y; bv[6] = (__bf16)v1.z; bv[7] = (__bf16)v1.w;
      *(bf16x8*)(As + cur * 8192 + tid * 16) = bv;
    }
  };

  const int wm    = wid >> 2;
  const int wn    = wid & 3;
  const int l15   = lane & 15;
  const int kap_r = (lane >> 4) ^ ((l15 >> 1) & 3);
  const int aoff  = wm * 4096 + l15 * 64 + kap_r * 16;
  const int boff  = wn * 4096 + l15 * 64 + kap_r * 16;

  f32x4 acc[4][4];
#pragma unroll
  for (int mi = 0; mi < 4; ++mi)
#pragma unroll
    for (int ni = 0; ni < 4; ++ni)
      acc[mi][ni] = f32x4{0.f, 0.f, 0.f, 0.f};

  stage(0, 0);

  for (int kk = 0; kk < KSTEPS; ++kk) {
    const int cur = kk & 1;
    __syncthreads();
    if (kk + 1 < KSTEPS) stage(cur ^ 1, kk + 1);

    const char* pA = As + cur * 8192;
    const char* pB = Bs + cur * 16384;
    bf16x8 av[4], bv[4];
#pragma unroll
    for (int mi = 0; mi < 4; ++mi) av[mi] = *(const bf16x8*)(pA + aoff + mi * 1024);
#pragma unroll
    for (int ni = 0; ni < 4; ++ni) bv[ni] = *(const bf16x8*)(pB + boff + ni * 1024);
#pragma unroll
    for (int mi = 0; mi < 4; ++mi)
#pragma unroll
      for (int ni = 0; ni < 4; ++ni)
        acc[mi][ni] = __builtin_amdgcn_mfma_f32_16x16x32_bf16(av[mi], bv[ni], acc[mi][ni], 0, 0, 0);
  }

  float b1c[4], w2c[4];
#pragma unroll
  for (int ni = 0; ni < 4; ++ni) {
    int n = wn * 64 + ni * 16 + l15;
    b1c[ni] = b1[n];
    w2c[ni] = w2[n];
  }

  float rowsum[4][4];
#pragma unroll
  for (int mi = 0; mi < 4; ++mi)
#pragma unroll
    for (int r = 0; r < 4; ++r) rowsum[mi][r] = 0.f;

#pragma unroll
  for (int ni = 0; ni < 4; ++ni) {
    float bbv = b1c[ni], ww = w2c[ni];
#pragma unroll
    for (int mi = 0; mi < 4; ++mi)
#pragma unroll
      for (int r = 0; r < 4; ++r) {
        float v  = acc[mi][ni][r] + bbv;
        float sv = v / (1.0f + __expf(-v));
        rowsum[mi][r] += sv * ww;
      }
  }

#pragma unroll
  for (int off = 1; off < 16; off <<= 1)
#pragma unroll
    for (int mi = 0; mi < 4; ++mi)
#pragma unroll
      for (int r = 0; r < 4; ++r)
        rowsum[mi][r] += __shfl_xor(rowsum[mi][r], off, 64);

  if (l15 == 0) {
    int rg = lane >> 4;
#pragma unroll
    for (int mi = 0; mi < 4; ++mi)
#pragma unroll
      for (int r = 0; r < 4; ++r)
        red[wn * 128 + wm * 64 + mi * 16 + rg * 4 + r] = rowsum[mi][r];
  }
  __syncthreads();

  if (tid < BM) {
    float v = red[tid] + red[128 + tid] + red[256 + tid] + red[384 + tid] + b2[0];
    out[blk * BM + tid] = v;
  }
}

// ---------------- launch ----------------
extern "C" void kernel_launch(void* const* d_in, const int* in_sizes, int n_in,
                              void* d_out, int out_size, void* d_ws, size_t ws_size,
                              hipStream_t stream) {
  const float* instr = (const float*)d_in[0];
  const float* x     = (const float*)d_in[1];
  const int*   ei    = (const int*)d_in[2];
  const int*   batch = (const int*)d_in[3];
  const float* W1    = (const float*)d_in[4];
  const float* b1    = (const float*)d_in[5];
  const float* W2    = (const float*)d_in[6];
  const float* b2    = (const float*)d_in[7];
  float* out = (float*)d_out;
  char* ws = (char*)d_ws;

  // full-path workspace layout
  const size_t off_xbf  = 0;                       // 12,800,000
  const size_t off_w1pt = 12800000;                // 131,072
  const size_t off_r2   = 12931072;                // 65,536
  const size_t off_pq   = 12996608;                // 51,200,000
  const size_t need_full = 64196608;

  if (ws_size >= need_full) {
    __bf16* xbf  = (__bf16*)(ws + off_xbf);
    __bf16* w1pt = (__bf16*)(ws + off_w1pt);
    float*  r2   = (float*)(ws + off_r2);
    __bf16* pq   = (__bf16*)(ws + off_pq);

    k_prep<<<PREP_CVT_BLKS + PREP_W1_BLKS + PREP_R2_BLKS, 256, 0, stream>>>(
        x, W1, instr, b1, xbf, w1pt, r2);
    dim3 g1((N_NODES_C + 127) / 128, 2);
    k_nodegemm<<<g1, 512, 0, stream>>>(xbf, w1pt, batch, r2, pq);
    k_edge<<<2048, 256, 0, stream>>>(pq, ei, W2, b2, out);
    return;
  }

  // fallback: round-1 fused edge GEMM
  const size_t f_off_xbf = 0;
  const size_t f_off_ins = 12800000;
  const size_t f_off_w1t = 12816384;
  const size_t need_fast = 13012992;

  if (ws_size >= need_fast) {
    __bf16* xbf   = (__bf16*)(ws + f_off_xbf);
    __bf16* insbf = (__bf16*)(ws + f_off_ins);
    __bf16* w1t   = (__bf16*)(ws + f_off_w1t);
    k_cvt4<<<(N_NODES_C * DD / 4 + 255) / 256, 256, 0, stream>>>(x, xbf, N_NODES_C * DD / 4);
    k_cvt4<<<(NG * DD / 4 + 255) / 256, 256, 0, stream>>>(instr, insbf, NG * DD / 4);
    k_w1t_fb<<<(KDIM * HH + 255) / 256, 256, 0, stream>>>(W1, w1t);
    k_main<0><<<E_EDGES / BM, THREADS, 0, stream>>>(x, instr, ei, batch, xbf, insbf, w1t,
                                                    b1, W2, b2, out);
  } else {
    __bf16* w1t = (__bf16*)ws;
    k_w1t_fb<<<(KDIM * HH + 255) / 256, 256, 0, stream>>>(W1, w1t);
    k_main<1><<<E_EDGES / BM, THREADS, 0, stream>>>(x, instr, ei, batch, nullptr, nullptr, w1t,
                                                    b1, W2, b2, out);
  }
}